// Round 1
// baseline (116.862 us; speedup 1.0000x reference)
//
#include <hip/hip_runtime.h>
#include <math.h>

#define N_CLASSES 1000
#define FEAT_DIM 1024
#define PROJ_DIM 256
#define BATCH 32
#define NUM_SUPPORT 8192

// prelude grid layout (unchanged from prior round)
#define PW_BLOCKS 16   // prep_w: 64-k tile each
#define PX_BLOCKS 256  // proj_x (32 b x 8 cc)

typedef __attribute__((ext_vector_type(8))) _Float16 f16x8;
typedef __attribute__((ext_vector_type(4))) float f32x4;
typedef __attribute__((ext_vector_type(16))) float f32x16;

// ---------------------------------------------------------------------------
// Prelude (one dispatch): prep_w (W->fp16 n-major) | proj_x (xqh2=fp16(2xW)).
// Branch is uniform per block.
// (-||xq_b||^2 is constant per batch row -> cancels in softmax.)
// ---------------------------------------------------------------------------
__global__ __launch_bounds__(256) void prelude_kernel(
    const float* __restrict__ W, const float* __restrict__ x,
    _Float16* __restrict__ W1, _Float16* __restrict__ xqh2) {
  __shared__ float part[256];
  __shared__ _Float16 Lw[256][66];  // transpose tile, padded
  const int bid = blockIdx.x;
  const int t = threadIdx.x;

  if (bid < PW_BLOCKS) {
    // ---- prep_w: W (k-major) -> W1 (n-major fp16) via LDS transpose.
    const int k0 = bid * 64;
#pragma unroll 8
    for (int kk = 0; kk < 64; kk++) {
      Lw[t][kk] = (_Float16)W[(size_t)(k0 + kk) * PROJ_DIM + t];
    }
    __syncthreads();
#pragma unroll
    for (int i = 0; i < 8; i++) {
      *(f16x8*)&W1[(size_t)t * FEAT_DIM + k0 + i * 8] = *(f16x8*)&Lw[t][i * 8];
    }
  } else {
    // ---- proj_x: xqh2[b][col] = fp16(2 * (x@W)[b][col])
    const int pxb = bid - PW_BLOCKS;
    const int b = pxb >> 3, cc = pxb & 7;
    const int col = t & 31, ks = t >> 5;
    const int gc = cc * 32 + col;
    const int k0 = ks * 128;
    float s = 0.f;
#pragma unroll 8
    for (int k = 0; k < 128; k++) {
      s = fmaf(x[(size_t)b * FEAT_DIM + k0 + k],
               W[(size_t)(k0 + k) * PROJ_DIM + gc], s);
    }
    part[t] = s;
    __syncthreads();
    if (t < 32) {
      float acc = 0.f;
#pragma unroll
      for (int i = 0; i < 8; i++) acc += part[i * 32 + t];
      xqh2[(size_t)b * PROJ_DIM + cc * 32 + t] = (_Float16)(2.0f * acc);
    }
  }
}

// ---------------------------------------------------------------------------
// gemm_score v2: 32x128 tile of sxp = fp16(sx) @ W1^T, mfma_f32_32x32x16_f16.
//  - 512 blocks (256 m-tiles x 2 n-tiles), 2 blocks/CU, 4 waves/block.
//  - Wave w owns n-slice [w*32, w*32+32): one f32x16 accumulator.
//  - A (sx fp32->fp16) double-buffered in LDS (shared by 4 waves), 1 barrier
//    per K-iter, 1-iter-ahead global prefetch.
//  - B (W1, L2-resident 0.5 MB) loaded REGISTER-DIRECT per kstep: no LDS
//    staging at all (each wave owns distinct rows -> zero reuse to exploit).
//  - Epilogue: rsq from fp32 acc via shfl_xor; sxp->Sx (fp16, XOR-swizzled);
//    score = 2xq.sxp - rsq via a second 32x32x16 MFMA (A=Sx rows j, B=Xl
//    rows b). Each wave computes full K redundantly, writes its reg-quarter.
//  - Partials: scP[ntile][b][j], ntile in {0,1}: write-once, no atomics.
// ---------------------------------------------------------------------------
__global__ __launch_bounds__(256) void gemm_score_kernel(
    const float* __restrict__ sx, const _Float16* __restrict__ W1,
    const _Float16* __restrict__ xqh2, float* __restrict__ scP) {
  __shared__ _Float16 At[2][32 * 64];  // A double-buffer, chunk-swizzled
  __shared__ _Float16 Sx[32 * 128];    // sxp tile fp16, chunk-swizzled
  __shared__ _Float16 Xl[32 * 128];    // 2*xq slice, chunk-swizzled
  __shared__ float Rp[4][32];          // per-wave rsq partials
  __shared__ float Rt[32];             // summed rsq

  const int tid = threadIdx.x;
  const int w = tid >> 6;
  const int lane = tid & 63;
  const int l31 = lane & 31;
  const int hi = lane >> 5;

  const int xcd = blockIdx.x & 7;
  const int idx = blockIdx.x >> 3;
  const int bm = (xcd * 32 + (idx & 31)) * 32;  // support row base
  const int ntile = idx >> 5;                   // 0..1
  const int bn = ntile * 128;                   // proj col base

  // ---- Xl: 32 b-rows x 128 halfs of 2*xq, stored with chunk XOR swizzle
  {
    const int r = tid >> 3;
    const int c0 = tid & 7;
#pragma unroll
    for (int cc = 0; cc < 2; cc++) {
      const int c = c0 + cc * 8;
      const int sw = (c & 8) | ((c & 7) ^ (r & 7));
      *(f16x8*)&Xl[r * 128 + sw * 8] =
          *(const f16x8*)&xqh2[(size_t)r * PROJ_DIM + bn + c * 8];
    }
  }

  // A staging ownership: thread -> row (tid>>3), chunk (tid&7), swizzled dest
  const int arow = tid >> 3;
  const int ac = tid & 7;
  const float* __restrict__ abase =
      sx + (size_t)(bm + arow) * FEAT_DIM + ac * 8;
  const int asw = (ac ^ (arow & 7)) * 8;

  // B register-direct base: wave w rows bn + w*32 + l31, k-offset hi*8
  const _Float16* __restrict__ bbase =
      W1 + (size_t)(bn + w * 32 + l31) * FEAT_DIM + hi * 8;

  f32x16 acc;
#pragma unroll
  for (int i = 0; i < 16; ++i) acc[i] = 0.f;

  // prologue: stage A(0), load B(0)
  {
    const float4* gp = (const float4*)abase;
    const float4 v0 = gp[0], v1 = gp[1];
    f16x8 h = {(_Float16)v0.x, (_Float16)v0.y, (_Float16)v0.z, (_Float16)v0.w,
               (_Float16)v1.x, (_Float16)v1.y, (_Float16)v1.z, (_Float16)v1.w};
    *(f16x8*)&At[0][arow * 64 + asw] = h;
  }
  f16x8 bcur[4];
#pragma unroll
  for (int ks = 0; ks < 4; ks++) bcur[ks] = *(const f16x8*)&bbase[ks * 16];
  __syncthreads();

#pragma unroll
  for (int t = 0; t < 16; ++t) {
    const int cur = t & 1;
    const int kb = t * 64;
    // issue next-iter loads first (latency hidden under MFMA below)
    float4 a0, a1;
    f16x8 bnx[4];
    if (t < 15) {
      const float4* gp = (const float4*)(abase + kb + 64);
      a0 = gp[0];
      a1 = gp[1];
#pragma unroll
      for (int ks = 0; ks < 4; ks++)
        bnx[ks] = *(const f16x8*)&bbase[kb + 64 + ks * 16];
    }
    // compute current: 4 ksteps of 32x32x16 (A frag: row=l31, k=hi*8+j)
#pragma unroll
    for (int ks = 0; ks < 4; ks++) {
      const int c = ks * 2 + hi;
      const int sw = (c ^ (l31 & 7)) * 8;
      const f16x8 af = *(const f16x8*)&At[cur][l31 * 64 + sw];
      acc = __builtin_amdgcn_mfma_f32_32x32x16_f16(af, bcur[ks], acc, 0, 0, 0);
    }
    // write A(t+1) into the other buffer; hand over B regs
    if (t < 15) {
      f16x8 h = {(_Float16)a0.x, (_Float16)a0.y, (_Float16)a0.z,
                 (_Float16)a0.w, (_Float16)a1.x, (_Float16)a1.y,
                 (_Float16)a1.z, (_Float16)a1.w};
      *(f16x8*)&At[cur ^ 1][arow * 64 + asw] = h;
#pragma unroll
      for (int ks = 0; ks < 4; ks++) bcur[ks] = bnx[ks];
    }
    __syncthreads();
  }

  // ---- rsq partials from fp32 acc.
  // C/D layout (32x32): col = l31 (n), row j = (r&3) + 8*(r>>2) + 4*hi.
#pragma unroll
  for (int r = 0; r < 16; ++r) {
    float p = acc[r] * acc[r];
#pragma unroll
    for (int m = 1; m <= 16; m <<= 1) p += __shfl_xor(p, m, 64);
    if (l31 == 0) Rp[w][(r & 3) + 8 * (r >> 2) + 4 * hi] = p;
  }
  // ---- Sx: sxp fp16 tile, chunk-swizzled for the score-MFMA frag reads
  {
    const int n = w * 32 + l31;
    const int cb = n >> 3, nin = n & 7;
#pragma unroll
    for (int r = 0; r < 16; ++r) {
      const int j = (r & 3) + 8 * (r >> 2) + 4 * hi;
      const int sw = (cb & 8) | ((cb & 7) ^ (j & 7));
      Sx[j * 128 + sw * 8 + nin] = (_Float16)acc[r];
    }
  }
  __syncthreads();
  if (tid < 32) Rt[tid] = Rp[0][tid] + Rp[1][tid] + Rp[2][tid] + Rp[3][tid];
  __syncthreads();

  // ---- score MFMA: D[j][b] = sum_k Sx[j][k] * Xl[b][k]  (K=128, 8 ksteps).
  // Each wave computes the full product redundantly (8 MFMA), then writes
  // only its register-quarter g=w -> each (j,b) written exactly once.
  f32x16 sc;
#pragma unroll
  for (int i = 0; i < 16; ++i) sc[i] = 0.f;
#pragma unroll
  for (int ks = 0; ks < 8; ++ks) {
    const int c = ks * 2 + hi;
    const int sw = ((c & 8) | ((c & 7) ^ (l31 & 7))) * 8;
    const f16x8 af = *(const f16x8*)&Sx[l31 * 128 + sw];
    const f16x8 bf = *(const f16x8*)&Xl[l31 * 128 + sw];
    sc = __builtin_amdgcn_mfma_f32_32x32x16_f16(af, bf, sc, 0, 0, 0);
  }
  {
    const int b = l31;
    const int j0 = 8 * w + 4 * hi;
    f32x4 v;
#pragma unroll
    for (int r = 0; r < 4; ++r) v[r] = sc[w * 4 + r] - Rt[j0 + r];
    float* __restrict__ outP = scP + (size_t)ntile * BATCH * NUM_SUPPORT;
    *(f32x4*)&outP[(size_t)b * NUM_SUPPORT + bm + j0] = v;
  }
}

// ---------------------------------------------------------------------------
// finish: per batch row: sum 2 partials, row max, exp, class bins, log.
// One block (1024 thr) per b; row values kept in registers between passes.
// ---------------------------------------------------------------------------
__global__ __launch_bounds__(1024) void finish_kernel(
    const float* __restrict__ scP, const int* __restrict__ sy,
    float* __restrict__ out) {
  __shared__ float cls[N_CLASSES];
  __shared__ float redm[16];
  __shared__ float reds[16];

  const int b = blockIdx.x;
  const int t = threadIdx.x;
  const int lane = t & 63, wave = t >> 6;
  const size_t P = (size_t)BATCH * NUM_SUPPORT;
  const float* __restrict__ row0 = scP + (size_t)b * NUM_SUPPORT;

  float v[8];
  float m = -1e30f;
#pragma unroll
  for (int jj = 0; jj < 8; jj++) {
    const size_t o = (size_t)jj * 1024 + t;
    v[jj] = row0[o] + row0[P + o];
    m = fmaxf(m, v[jj]);
  }
#pragma unroll
  for (int o = 1; o < 64; o <<= 1) m = fmaxf(m, __shfl_xor(m, o, 64));
  if (lane == 0) redm[wave] = m;
  if (t < N_CLASSES) cls[t] = 0.0f;
  __syncthreads();
  float gm = redm[0];
#pragma unroll
  for (int i = 1; i < 16; i++) gm = fmaxf(gm, redm[i]);

  float lsum = 0.0f;
#pragma unroll
  for (int jj = 0; jj < 8; jj++) {
    const float e = expf(v[jj] - gm);
    lsum += e;
    atomicAdd(&cls[sy[jj * 1024 + t]], e);
  }
#pragma unroll
  for (int o = 1; o < 64; o <<= 1) lsum += __shfl_xor(lsum, o, 64);
  if (lane == 0) reds[wave] = lsum;
  __syncthreads();
  float total = 0.f;
#pragma unroll
  for (int i = 0; i < 16; i++) total += reds[i];
  const float inv = 1.0f / total;
  if (t < N_CLASSES) {
    out[(size_t)b * N_CLASSES + t] = logf(cls[t] * inv + 1e-12f);
  }
}

// ---------------------------------------------------------------------------
extern "C" void kernel_launch(void* const* d_in, const int* in_sizes, int n_in,
                              void* d_out, int out_size, void* d_ws,
                              size_t ws_size, hipStream_t stream) {
  const float* x = (const float*)d_in[0];   // (32, 1024)
  const float* sx = (const float*)d_in[1];  // (8192, 1024)
  const float* W = (const float*)d_in[2];   // (1024, 256)
  const int* sy = (const int*)d_in[3];      // (8192,)
  float* out = (float*)d_out;               // (32, 1000)

  char* p = (char*)d_ws;
  float* scP = (float*)p;         p += (size_t)2 * BATCH * NUM_SUPPORT * 4;
  _Float16* W1 = (_Float16*)p;    p += (size_t)PROJ_DIM * FEAT_DIM * 2;
  _Float16* xqh2 = (_Float16*)p;  // 32*256*2

  prelude_kernel<<<dim3(PW_BLOCKS + PX_BLOCKS), dim3(256), 0, stream>>>(
      W, x, W1, xqh2);
  gemm_score_kernel<<<dim3(512), dim3(256), 0, stream>>>(sx, W1, xqh2, scP);
  finish_kernel<<<dim3(BATCH), dim3(1024), 0, stream>>>(scP, sy, out);
}

// Round 2
// 113.746 us; speedup vs baseline: 1.0274x; 1.0274x over previous
//
#include <hip/hip_runtime.h>
#include <math.h>

#define N_CLASSES 1000
#define FEAT_DIM 1024
#define PROJ_DIM 256
#define BATCH 32
#define NUM_SUPPORT 8192

// prelude grid layout (prep_a deleted; sc-zero deleted: partial buffers are
// write-once so no zeroing needed)
#define PW_BLOCKS 16   // prep_w: 64-k tile each
#define PX_BLOCKS 256  // proj_x (32 b x 8 cc)

typedef __attribute__((ext_vector_type(8))) _Float16 f16x8;
typedef __attribute__((ext_vector_type(2))) _Float16 f16x2;
typedef __attribute__((ext_vector_type(4))) float f32x4;

// ---------------------------------------------------------------------------
// Prelude (one dispatch): prep_w (W->fp16 n-major) | proj_x (xqh2=fp16(2xW)).
// Branch is uniform per block.
// (-||xq_b||^2 is constant per batch row -> cancels in softmax.)
// ---------------------------------------------------------------------------
__global__ __launch_bounds__(256) void prelude_kernel(
    const float* __restrict__ W, const float* __restrict__ x,
    _Float16* __restrict__ W1, _Float16* __restrict__ xqh2) {
  __shared__ float part[256];
  __shared__ _Float16 Lw[256][66];  // transpose tile, padded
  const int bid = blockIdx.x;
  const int t = threadIdx.x;

  if (bid < PW_BLOCKS) {
    // ---- prep_w: W (k-major) -> W1 (n-major fp16) via LDS transpose.
    const int k0 = bid * 64;
#pragma unroll 8
    for (int kk = 0; kk < 64; kk++) {
      Lw[t][kk] = (_Float16)W[(size_t)(k0 + kk) * PROJ_DIM + t];
    }
    __syncthreads();
#pragma unroll
    for (int i = 0; i < 8; i++) {
      *(f16x8*)&W1[(size_t)t * FEAT_DIM + k0 + i * 8] = *(f16x8*)&Lw[t][i * 8];
    }
  } else {
    // ---- proj_x: xqh2[b][col] = fp16(2 * (x@W)[b][col])
    const int pxb = bid - PW_BLOCKS;
    const int b = pxb >> 3, cc = pxb & 7;
    const int col = t & 31, ks = t >> 5;
    const int gc = cc * 32 + col;
    const int k0 = ks * 128;
    float s = 0.f;
#pragma unroll 8
    for (int k = 0; k < 128; k++) {
      s = fmaf(x[(size_t)b * FEAT_DIM + k0 + k],
               W[(size_t)(k0 + k) * PROJ_DIM + gc], s);
    }
    part[t] = s;
    __syncthreads();
    if (t < 32) {
      float acc = 0.f;
#pragma unroll
      for (int i = 0; i < 8; i++) acc += part[i * 32 + t];
      xqh2[(size_t)b * PROJ_DIM + cc * 32 + t] = (_Float16)(2.0f * acc);
    }
  }
}

// ---------------------------------------------------------------------------
// gemm_score v3: round-0 structure (32x64 tile, 1024 blocks, 4 blocks/CU,
// 16x16x32 MFMA, fdot2 score epilogue) with ONE change: the K-loop is now
// the T3-minimum 2-phase schedule. At/Bt are double-buffered; iteration
// t+1's loads (A fp32 prefetch into regs + B global_load_lds) are issued
// BEFORE iteration t's MFMA phase, and there is a single __syncthreads()
// per iteration. The barrier's implicit vmcnt/lgkm drain now happens after
// the loads have had the whole compute phase to land, instead of stalling
// immediately (round-0 issued loads right before the drain -> zero overlap).
// Grid 1024 flat: xcd=bid&7, idx=bid>>3, m-tile=xcd*32+(idx&31) (32 rows),
// n-tile=idx>>5 -> all 4 n-tiles of one m-tile on one XCD (A L2-resident).
// ---------------------------------------------------------------------------
__global__ __launch_bounds__(256) void gemm_score_kernel(
    const float* __restrict__ sx, const _Float16* __restrict__ W1,
    const _Float16* __restrict__ xqh2, float* __restrict__ scP) {
  __shared__ _Float16 At[2][32 * 64];  // A staging dbuf, XOR-swizzled chunks
  __shared__ _Float16 Bt[2][64 * 64];  // B staging dbuf (gload_lds, linear)
  __shared__ _Float16 Sx[32 * 72];     // sxp tile, padded stride 72
  __shared__ _Float16 Xl[32 * 64];     // 2*xq slice for this n-chunk

  const int tid = threadIdx.x;
  const int w = tid >> 6;
  const int lane = tid & 63;
  const int xcd = blockIdx.x & 7;
  const int idx = blockIdx.x >> 3;
  const int bm = (xcd * 32 + (idx & 31)) * 32;  // 0..255 m-tiles of 32 rows
  const int ntile = idx >> 5;                   // 0..3
  const int bn = ntile * 64;
  const int wm = w & 1, wn = w >> 1;
  const int m16 = lane & 15, quad = lane >> 4;
  const int lrow8 = lane >> 3;        // 0..7
  const int gB = (lane & 7) ^ lrow8;  // XOR-swizzled global chunk (B path)

  // load Xl: 32 b-rows x 64 halfs (this block's n-range)
  {
    const int r = tid >> 3, c = tid & 7;
    *(f16x8*)&Xl[r * 64 + c * 8] =
        *(const f16x8*)&xqh2[(size_t)r * PROJ_DIM + bn + c * 8];
  }

  // A staging: thread owns row = tid>>3 (0..31), chunk c = tid&7 (8 halfs =
  // 8 fp32). Written to LDS position c^(row&7) — MFMA read path unchanged.
  const int arow = tid >> 3;
  const int ac = tid & 7;
  const float* __restrict__ abase =
      sx + (size_t)(bm + arow) * FEAT_DIM + ac * 8;
  const int asw = (ac ^ (arow & 7)) * 8;

  f32x4 acc[2];
#pragma unroll
  for (int nt = 0; nt < 2; nt++) acc[nt] = (f32x4){0.f, 0.f, 0.f, 0.f};

  // ---- prologue: stage A(0) + issue B(0), then one barrier.
  {
    const float4* gp = (const float4*)abase;
    const float4 v0 = gp[0], v1 = gp[1];
    f16x8 h0 = {(_Float16)v0.x, (_Float16)v0.y, (_Float16)v0.z, (_Float16)v0.w,
                (_Float16)v1.x, (_Float16)v1.y, (_Float16)v1.z, (_Float16)v1.w};
    *(f16x8*)&At[0][arow * 64 + asw] = h0;
  }
#pragma unroll
  for (int i = 0; i < 2; i++) {
    const int nrow = w * 16 + i * 8 + lrow8;
    const _Float16* gp = W1 + (size_t)(bn + nrow) * FEAT_DIM + gB * 8;
    __builtin_amdgcn_global_load_lds(
        (const __attribute__((address_space(1))) void*)gp,
        (__attribute__((address_space(3))) void*)(Bt[0] +
                                                  (w * 16 + i * 8) * 64),
        16, 0, 0);
  }
  __syncthreads();

  // ---- main loop: one barrier per K-iter; next-iter loads issued first so
  // they overlap this iter's MFMA phase.
  for (int t = 0; t < 16; ++t) {
    const int cur = t & 1;
    const int nb = cur ^ 1;
    const int kb = t * 64;

    float4 a0, a1;
    if (t < 15) {
      // A(t+1): global fp32 -> regs (convert+write after MFMA below)
      const float4* gp = (const float4*)(abase + kb + 64);
      a0 = gp[0];
      a1 = gp[1];
      // B(t+1): 2 async direct-to-LDS loads into the other buffer
#pragma unroll
      for (int i = 0; i < 2; i++) {
        const int nrow = w * 16 + i * 8 + lrow8;
        const _Float16* gp2 =
            W1 + (size_t)(bn + nrow) * FEAT_DIM + kb + 64 + gB * 8;
        __builtin_amdgcn_global_load_lds(
            (const __attribute__((address_space(1))) void*)gp2,
            (__attribute__((address_space(3))) void*)(Bt[nb] +
                                                      (w * 16 + i * 8) * 64),
            16, 0, 0);
      }
    }

    // compute current buffer
#pragma unroll
    for (int s = 0; s < 2; s++) {
      const int slot = (s * 4 + quad) ^ (m16 & 7);
      f16x8 af, bf[2];
      {
        const int row = wm * 16 + m16;
        af = *(f16x8*)&At[cur][row * 64 + slot * 8];
      }
#pragma unroll
      for (int nt = 0; nt < 2; nt++) {
        const int nrow = wn * 32 + nt * 16 + m16;
        bf[nt] = *(f16x8*)&Bt[cur][nrow * 64 + slot * 8];
      }
#pragma unroll
      for (int nt = 0; nt < 2; nt++)
        acc[nt] = __builtin_amdgcn_mfma_f32_16x16x32_f16(af, bf[nt], acc[nt],
                                                         0, 0, 0);
    }

    // A(t+1): convert + swizzled LDS write (loads have had MFMA phase to land)
    if (t < 15) {
      f16x8 h = {(_Float16)a0.x, (_Float16)a0.y, (_Float16)a0.z,
                 (_Float16)a0.w, (_Float16)a1.x, (_Float16)a1.y,
                 (_Float16)a1.z, (_Float16)a1.w};
      *(f16x8*)&At[nb][arow * 64 + asw] = h;
    }
    __syncthreads();
  }

  // ---- epilogue: sxp tile -> LDS (fp16, padded stride 72).
  // C/D layout: col = lane&15 (n), row = quad*4 + reg (m/j)
#pragma unroll
  for (int nt = 0; nt < 2; nt++)
#pragma unroll
    for (int r = 0; r < 4; r++) {
      const int jl = wm * 16 + quad * 4 + r;
      const int nl = wn * 32 + nt * 16 + m16;
      Sx[jl * 72 + nl] = (_Float16)acc[nt][r];
    }
  __syncthreads();

  // ---- fused partial score: thread t -> j = t&31, b-group = t>>5 (4 b's).
  // Half-wave shares b-group -> Xl reads are 2-address broadcasts (free).
  const int j = tid & 31;
  const int bg = tid >> 5;
  float dotb[4] = {0.f, 0.f, 0.f, 0.f};
  float rsq = 0.f;
#pragma unroll
  for (int c = 0; c < 8; c++) {
    const f16x8 hv = *(const f16x8*)&Sx[j * 72 + c * 8];
    const f16x2* hp = (const f16x2*)&hv;
#pragma unroll
    for (int i = 0; i < 4; i++)
      rsq = __builtin_amdgcn_fdot2(hp[i], hp[i], rsq, false);
#pragma unroll
    for (int b4 = 0; b4 < 4; b4++) {
      const f16x8 xv = *(const f16x8*)&Xl[(bg * 4 + b4) * 64 + c * 8];
      const f16x2* xp = (const f16x2*)&xv;
#pragma unroll
      for (int i = 0; i < 4; i++)
        dotb[b4] = __builtin_amdgcn_fdot2(hp[i], xp[i], dotb[b4], false);
    }
  }
  // write-once partial stores (no atomics, no zero-init)
  float* __restrict__ outP = scP + (size_t)ntile * BATCH * NUM_SUPPORT;
#pragma unroll
  for (int b4 = 0; b4 < 4; b4++) {
    outP[(size_t)(bg * 4 + b4) * NUM_SUPPORT + bm + j] = dotb[b4] - rsq;
  }
}

// ---------------------------------------------------------------------------
// finish: per batch row: sum 4 partials, row max, exp, class bins, log.
// One block (1024 thr) per b; row values kept in registers between passes.
// ---------------------------------------------------------------------------
__global__ __launch_bounds__(1024) void finish_kernel(
    const float* __restrict__ scP, const int* __restrict__ sy,
    float* __restrict__ out) {
  __shared__ float cls[N_CLASSES];
  __shared__ float redm[16];
  __shared__ float reds[16];

  const int b = blockIdx.x;
  const int t = threadIdx.x;
  const int lane = t & 63, wave = t >> 6;
  const size_t P = (size_t)BATCH * NUM_SUPPORT;
  const float* __restrict__ row0 = scP + (size_t)b * NUM_SUPPORT;

  float v[8];
  float m = -1e30f;
#pragma unroll
  for (int jj = 0; jj < 8; jj++) {
    const size_t o = (size_t)jj * 1024 + t;
    v[jj] = (row0[o] + row0[P + o]) + (row0[2 * P + o] + row0[3 * P + o]);
    m = fmaxf(m, v[jj]);
  }
#pragma unroll
  for (int o = 1; o < 64; o <<= 1) m = fmaxf(m, __shfl_xor(m, o, 64));
  if (lane == 0) redm[wave] = m;
  if (t < N_CLASSES) cls[t] = 0.0f;
  __syncthreads();
  float gm = redm[0];
#pragma unroll
  for (int i = 1; i < 16; i++) gm = fmaxf(gm, redm[i]);

  float lsum = 0.0f;
#pragma unroll
  for (int jj = 0; jj < 8; jj++) {
    const float e = expf(v[jj] - gm);
    lsum += e;
    atomicAdd(&cls[sy[jj * 1024 + t]], e);
  }
#pragma unroll
  for (int o = 1; o < 64; o <<= 1) lsum += __shfl_xor(lsum, o, 64);
  if (lane == 0) reds[wave] = lsum;
  __syncthreads();
  float total = 0.f;
#pragma unroll
  for (int i = 0; i < 16; i++) total += reds[i];
  const float inv = 1.0f / total;
  if (t < N_CLASSES) {
    out[(size_t)b * N_CLASSES + t] = logf(cls[t] * inv + 1e-12f);
  }
}

// ---------------------------------------------------------------------------
extern "C" void kernel_launch(void* const* d_in, const int* in_sizes, int n_in,
                              void* d_out, int out_size, void* d_ws,
                              size_t ws_size, hipStream_t stream) {
  const float* x = (const float*)d_in[0];   // (32, 1024)
  const float* sx = (const float*)d_in[1];  // (8192, 1024)
  const float* W = (const float*)d_in[2];   // (1024, 256)
  const int* sy = (const int*)d_in[3];      // (8192,)
  float* out = (float*)d_out;               // (32, 1000)

  char* p = (char*)d_ws;
  float* scP = (float*)p;         p += (size_t)4 * BATCH * NUM_SUPPORT * 4;
  _Float16* W1 = (_Float16*)p;    p += (size_t)PROJ_DIM * FEAT_DIM * 2;
  _Float16* xqh2 = (_Float16*)p;  // 32*256*2

  prelude_kernel<<<dim3(PW_BLOCKS + PX_BLOCKS), dim3(256), 0, stream>>>(
      W, x, W1, xqh2);
  gemm_score_kernel<<<dim3(1024), dim3(256), 0, stream>>>(sx, W1, xqh2, scP);
  finish_kernel<<<dim3(BATCH), dim3(1024), 0, stream>>>(scP, sy, out);
}

// Round 4
// 109.500 us; speedup vs baseline: 1.0672x; 1.0388x over previous
//
#include <hip/hip_runtime.h>
#include <math.h>

#define N_CLASSES 1000
#define FEAT_DIM 1024
#define PROJ_DIM 256
#define BATCH 32
#define NUM_SUPPORT 8192

// prelude grid layout
#define PW_BLOCKS 16   // prep_w: 64-k tile each
#define PX_BLOCKS 256  // proj_x (32 b x 8 cc)

typedef __attribute__((ext_vector_type(8))) _Float16 f16x8;
typedef __attribute__((ext_vector_type(2))) _Float16 f16x2;
typedef __attribute__((ext_vector_type(4))) float f32x4;

// ---------------------------------------------------------------------------
// Prelude (one dispatch): prep_w (W->fp16 n-major) | proj_x (xqh2=fp16(2xW)).
// Branch is uniform per block.
// (-||xq_b||^2 is constant per batch row -> cancels in softmax.)
// proj_x change vs round-0: 4 independent accumulators break the serial
// 128-deep fmaf dependency chain (was the latency floor of this branch).
// ---------------------------------------------------------------------------
__global__ __launch_bounds__(256) void prelude_kernel(
    const float* __restrict__ W, const float* __restrict__ x,
    _Float16* __restrict__ W1, _Float16* __restrict__ xqh2) {
  __shared__ float part[256];
  __shared__ _Float16 Lw[256][66];  // transpose tile, padded
  const int bid = blockIdx.x;
  const int t = threadIdx.x;

  if (bid < PW_BLOCKS) {
    // ---- prep_w: W (k-major) -> W1 (n-major fp16) via LDS transpose.
    const int k0 = bid * 64;
#pragma unroll 8
    for (int kk = 0; kk < 64; kk++) {
      Lw[t][kk] = (_Float16)W[(size_t)(k0 + kk) * PROJ_DIM + t];
    }
    __syncthreads();
#pragma unroll
    for (int i = 0; i < 8; i++) {
      *(f16x8*)&W1[(size_t)t * FEAT_DIM + k0 + i * 8] = *(f16x8*)&Lw[t][i * 8];
    }
  } else {
    // ---- proj_x: xqh2[b][col] = fp16(2 * (x@W)[b][col])
    const int pxb = bid - PW_BLOCKS;
    const int b = pxb >> 3, cc = pxb & 7;
    const int col = t & 31, ks = t >> 5;
    const int gc = cc * 32 + col;
    const int k0 = ks * 128;
    float s0 = 0.f, s1 = 0.f, s2 = 0.f, s3 = 0.f;
#pragma unroll 8
    for (int k = 0; k < 128; k += 4) {
      s0 = fmaf(x[(size_t)b * FEAT_DIM + k0 + k],
                W[(size_t)(k0 + k) * PROJ_DIM + gc], s0);
      s1 = fmaf(x[(size_t)b * FEAT_DIM + k0 + k + 1],
                W[(size_t)(k0 + k + 1) * PROJ_DIM + gc], s1);
      s2 = fmaf(x[(size_t)b * FEAT_DIM + k0 + k + 2],
                W[(size_t)(k0 + k + 2) * PROJ_DIM + gc], s2);
      s3 = fmaf(x[(size_t)b * FEAT_DIM + k0 + k + 3],
                W[(size_t)(k0 + k + 3) * PROJ_DIM + gc], s3);
    }
    part[t] = (s0 + s1) + (s2 + s3);
    __syncthreads();
    if (t < 32) {
      float acc = 0.f;
#pragma unroll
      for (int i = 0; i < 8; i++) acc += part[i * 32 + t];
      xqh2[(size_t)b * PROJ_DIM + cc * 32 + t] = (_Float16)(2.0f * acc);
    }
  }
}

// ---------------------------------------------------------------------------
// gemm_score: EXACT round-0 version (best measured: 111.2 us total).
// 32x64 tile of sxp = fp16(sx) @ W1^T (MFMA, K=1024), 4 blocks/CU.
// In-register fp32->fp16 A staging with XOR chunk swizzle c^(row&7).
// Fused score epilogue writes WRITE-ONCE partials scP[ntile][b][j] — no
// atomics, no zero-init. Grid 1024 flat: xcd=bid&7, idx=bid>>3,
// m-tile=xcd*32+(idx&31), n-tile=idx>>5 -> all 4 n-tiles of one m-tile on
// one XCD (A L2-resident).
// ---------------------------------------------------------------------------
__global__ __launch_bounds__(256) void gemm_score_kernel(
    const float* __restrict__ sx, const _Float16* __restrict__ W1,
    const _Float16* __restrict__ xqh2, float* __restrict__ scP) {
  __shared__ _Float16 At[32 * 64];  // staging, XOR-swizzled chunks
  __shared__ _Float16 Bt[64 * 64];
  __shared__ _Float16 Sx[32 * 72];  // sxp tile, padded stride 72
  __shared__ _Float16 Xl[32 * 64];  // 2*xq slice for this n-chunk

  const int tid = threadIdx.x;
  const int w = tid >> 6;
  const int lane = tid & 63;
  const int xcd = blockIdx.x & 7;
  const int idx = blockIdx.x >> 3;
  const int bm = (xcd * 32 + (idx & 31)) * 32;  // 0..255 m-tiles of 32 rows
  const int ntile = idx >> 5;                   // 0..3
  const int bn = ntile * 64;
  const int wm = w & 1, wn = w >> 1;
  const int m16 = lane & 15, quad = lane >> 4;
  const int lrow8 = lane >> 3;        // 0..7
  const int gB = (lane & 7) ^ lrow8;  // XOR-swizzled global chunk (B path)

  // load Xl: 32 b-rows x 64 halfs (this block's n-range)
  {
    const int r = tid >> 3, c = tid & 7;
    *(f16x8*)&Xl[r * 64 + c * 8] =
        *(const f16x8*)&xqh2[(size_t)r * PROJ_DIM + bn + c * 8];
  }

  // A staging: thread owns row = tid>>3 (0..31), chunk c = tid&7 (8 halfs =
  // 8 fp32). Written to LDS position c^(row&7) — MFMA read path unchanged.
  const int arow = tid >> 3;
  const int ac = tid & 7;
  const float* __restrict__ abase =
      sx + (size_t)(bm + arow) * FEAT_DIM + ac * 8;
  _Float16* __restrict__ ad = &At[arow * 64 + (ac ^ (arow & 7)) * 8];

  f32x4 acc[2];
#pragma unroll
  for (int nt = 0; nt < 2; nt++) acc[nt] = (f32x4){0.f, 0.f, 0.f, 0.f};

  for (int kb = 0; kb < FEAT_DIM; kb += 64) {
    // stage A: 8 fp32 -> 8 fp16, one swizzled b128 LDS write
    {
      const float4* gp = (const float4*)(abase + kb);
      const float4 v0 = gp[0], v1 = gp[1];
      f16x8 h0 = {(_Float16)v0.x, (_Float16)v0.y, (_Float16)v0.z,
                  (_Float16)v0.w, (_Float16)v1.x, (_Float16)v1.y,
                  (_Float16)v1.z, (_Float16)v1.w};
      *(f16x8*)ad = h0;
    }
    // stage B tile (64 n x 64 k fp16): 2 async instrs/wave
#pragma unroll
    for (int i = 0; i < 2; i++) {
      const int nrow = w * 16 + i * 8 + lrow8;
      const _Float16* gp = W1 + (size_t)(bn + nrow) * FEAT_DIM + kb + gB * 8;
      __builtin_amdgcn_global_load_lds(
          (const __attribute__((address_space(1))) void*)gp,
          (__attribute__((address_space(3))) void*)(Bt + (w * 16 + i * 8) * 64),
          16, 0, 0);
    }
    __syncthreads();

#pragma unroll
    for (int s = 0; s < 2; s++) {
      const int slot = (s * 4 + quad) ^ (m16 & 7);
      f16x8 af, bf[2];
      {
        const int row = wm * 16 + m16;
        af = *(f16x8*)&At[row * 64 + slot * 8];
      }
#pragma unroll
      for (int nt = 0; nt < 2; nt++) {
        const int nrow = wn * 32 + nt * 16 + m16;
        bf[nt] = *(f16x8*)&Bt[nrow * 64 + slot * 8];
      }
#pragma unroll
      for (int nt = 0; nt < 2; nt++)
        acc[nt] = __builtin_amdgcn_mfma_f32_16x16x32_f16(af, bf[nt], acc[nt],
                                                         0, 0, 0);
    }
    __syncthreads();
  }

  // ---- epilogue: sxp tile -> LDS (fp16, padded stride 72).
  // C/D layout: col = lane&15 (n), row = quad*4 + reg (m/j)
#pragma unroll
  for (int nt = 0; nt < 2; nt++)
#pragma unroll
    for (int r = 0; r < 4; r++) {
      const int jl = wm * 16 + quad * 4 + r;
      const int nl = wn * 32 + nt * 16 + m16;
      Sx[jl * 72 + nl] = (_Float16)acc[nt][r];
    }
  __syncthreads();

  // ---- fused partial score: thread t -> j = t&31, b-group = t>>5 (4 b's).
  // Half-wave shares b-group -> Xl reads are 2-address broadcasts (free).
  const int j = tid & 31;
  const int bg = tid >> 5;
  float dotb[4] = {0.f, 0.f, 0.f, 0.f};
  float rsq = 0.f;
#pragma unroll
  for (int c = 0; c < 8; c++) {
    const f16x8 hv = *(const f16x8*)&Sx[j * 72 + c * 8];
    const f16x2* hp = (const f16x2*)&hv;
#pragma unroll
    for (int i = 0; i < 4; i++)
      rsq = __builtin_amdgcn_fdot2(hp[i], hp[i], rsq, false);
#pragma unroll
    for (int b4 = 0; b4 < 4; b4++) {
      const f16x8 xv = *(const f16x8*)&Xl[(bg * 4 + b4) * 64 + c * 8];
      const f16x2* xp = (const f16x2*)&xv;
#pragma unroll
      for (int i = 0; i < 4; i++)
        dotb[b4] = __builtin_amdgcn_fdot2(hp[i], xp[i], dotb[b4], false);
    }
  }
  // write-once partial stores (no atomics, no zero-init)
  float* __restrict__ outP = scP + (size_t)ntile * BATCH * NUM_SUPPORT;
#pragma unroll
  for (int b4 = 0; b4 < 4; b4++) {
    outP[(size_t)(bg * 4 + b4) * NUM_SUPPORT + bm + j] = dotb[b4] - rsq;
  }
}

// ---------------------------------------------------------------------------
// finish: per batch row: sum 4 partials, row max, exp, class bins, log.
// One block (1024 thr) per b. Round-3 change: per-thread-contiguous 8-j
// layout with f32x4 loads (8 dwordx4 instead of 32 scalar loads/thread)
// and int4 label loads. Wave reads 2 KB contiguous per load instr.
// ---------------------------------------------------------------------------
__global__ __launch_bounds__(1024) void finish_kernel(
    const float* __restrict__ scP, const int* __restrict__ sy,
    float* __restrict__ out) {
  __shared__ float cls[N_CLASSES];
  __shared__ float redm[16];
  __shared__ float reds[16];

  const int b = blockIdx.x;
  const int t = threadIdx.x;
  const int lane = t & 63, wave = t >> 6;
  const size_t P = (size_t)BATCH * NUM_SUPPORT;
  const float* __restrict__ row0 =
      scP + (size_t)b * NUM_SUPPORT + (size_t)t * 8;

  // sum the 4 write-once partials with vector loads; track row max
  f32x4 sA, sB;
  {
    const f32x4 a0 = *(const f32x4*)(row0);
    const f32x4 a1 = *(const f32x4*)(row0 + P);
    const f32x4 a2 = *(const f32x4*)(row0 + 2 * P);
    const f32x4 a3 = *(const f32x4*)(row0 + 3 * P);
    sA = (a0 + a1) + (a2 + a3);
    const f32x4 b0 = *(const f32x4*)(row0 + 4);
    const f32x4 b1 = *(const f32x4*)(row0 + P + 4);
    const f32x4 b2 = *(const f32x4*)(row0 + 2 * P + 4);
    const f32x4 b3 = *(const f32x4*)(row0 + 3 * P + 4);
    sB = (b0 + b1) + (b2 + b3);
  }
  float m = -1e30f;
#pragma unroll
  for (int q = 0; q < 4; q++) m = fmaxf(m, fmaxf(sA[q], sB[q]));
#pragma unroll
  for (int o = 1; o < 64; o <<= 1) m = fmaxf(m, __shfl_xor(m, o, 64));
  if (lane == 0) redm[wave] = m;
  if (t < N_CLASSES) cls[t] = 0.0f;
  __syncthreads();
  float gm = redm[0];
#pragma unroll
  for (int i = 1; i < 16; i++) gm = fmaxf(gm, redm[i]);

  // exp + class binning (labels via two int4 loads)
  const int4 y0 = *(const int4*)(sy + t * 8);
  const int4 y1 = *(const int4*)(sy + t * 8 + 4);
  float lsum = 0.0f;
  {
    const float e0 = expf(sA[0] - gm);
    const float e1 = expf(sA[1] - gm);
    const float e2 = expf(sA[2] - gm);
    const float e3 = expf(sA[3] - gm);
    lsum += (e0 + e1) + (e2 + e3);
    atomicAdd(&cls[y0.x], e0);
    atomicAdd(&cls[y0.y], e1);
    atomicAdd(&cls[y0.z], e2);
    atomicAdd(&cls[y0.w], e3);
  }
  {
    const float e0 = expf(sB[0] - gm);
    const float e1 = expf(sB[1] - gm);
    const float e2 = expf(sB[2] - gm);
    const float e3 = expf(sB[3] - gm);
    lsum += (e0 + e1) + (e2 + e3);
    atomicAdd(&cls[y1.x], e0);
    atomicAdd(&cls[y1.y], e1);
    atomicAdd(&cls[y1.z], e2);
    atomicAdd(&cls[y1.w], e3);
  }
#pragma unroll
  for (int o = 1; o < 64; o <<= 1) lsum += __shfl_xor(lsum, o, 64);
  if (lane == 0) reds[wave] = lsum;
  __syncthreads();
  float total = 0.f;
#pragma unroll
  for (int i = 0; i < 16; i++) total += reds[i];
  const float inv = 1.0f / total;
  if (t < N_CLASSES) {
    out[(size_t)b * N_CLASSES + t] = logf(cls[t] * inv + 1e-12f);
  }
}

// ---------------------------------------------------------------------------
extern "C" void kernel_launch(void* const* d_in, const int* in_sizes, int n_in,
                              void* d_out, int out_size, void* d_ws,
                              size_t ws_size, hipStream_t stream) {
  const float* x = (const float*)d_in[0];   // (32, 1024)
  const float* sx = (const float*)d_in[1];  // (8192, 1024)
  const float* W = (const float*)d_in[2];   // (1024, 256)
  const int* sy = (const int*)d_in[3];      // (8192,)
  float* out = (float*)d_out;               // (32, 1000)

  char* p = (char*)d_ws;
  float* scP = (float*)p;         p += (size_t)4 * BATCH * NUM_SUPPORT * 4;
  _Float16* W1 = (_Float16*)p;    p += (size_t)PROJ_DIM * FEAT_DIM * 2;
  _Float16* xqh2 = (_Float16*)p;  // 32*256*2

  prelude_kernel<<<dim3(PW_BLOCKS + PX_BLOCKS), dim3(256), 0, stream>>>(
      W, x, W1, xqh2);
  gemm_score_kernel<<<dim3(1024), dim3(256), 0, stream>>>(sx, W1, xqh2, scP);
  finish_kernel<<<dim3(BATCH), dim3(1024), 0, stream>>>(scP, sy, out);
}